// Round 5
// baseline (160.033 us; speedup 1.0000x reference)
//
#include <hip/hip_runtime.h>
#include <stdint.h>

#define DIN 96
#define DP 48
#define NPOS (48*48*48)   // 110592
#define NG 1728           // 12^3
#define WIN3 343
#define NCH 64
#define NC2 32
#define PTILE 128

// ---------------------------------------------------------------------------
// Kernel A: depthwise 3x3x3 stride-2 pad-1 conv + bias -> dwout[c][pos]
// 2(d) x 1(h) x 4(w) micro-tile per thread; at HBM roofline (~183 MB fetch).
// ---------------------------------------------------------------------------
__global__ __launch_bounds__(256) void dwconv8(
    const float* __restrict__ feat,   // [64][96][96][96]
    const float* __restrict__ dw_w,   // [64][27]
    const float* __restrict__ dw_b,   // [64]
    float* __restrict__ dwout)        // [64][NPOS]
{
    const int c   = blockIdx.y;
    const int idx = blockIdx.x * 256 + threadIdx.x;   // 0..13823
    const int t   = idx % 12;                         // w-quad (out w = 4t..4t+3)
    const int oh  = (idx / 12) % 48;
    const int odp = idx / (12 * 48);                  // d-pair (out d = 2odp,2odp+1)

    const float* fc = feat + (size_t)c * (DIN * DIN * DIN);
    const float* wc = dw_w + c * 27;
    float w[27];
    #pragma unroll
    for (int i = 0; i < 27; ++i) w[i] = wc[i];        // wave-uniform

    float acc[2][4];
    #pragma unroll
    for (int i = 0; i < 2; ++i)
        #pragma unroll
        for (int j = 0; j < 4; ++j) acc[i][j] = 0.0f;

    #pragma unroll
    for (int dd = 0; dd < 5; ++dd) {
        const int id = 4 * odp - 1 + dd;              // input plane
        if (id >= 0) {
            #pragma unroll
            for (int kh = 0; kh < 3; ++kh) {
                const int ih = 2 * oh - 1 + kh;       // input row
                if (ih >= 0) {
                    const float* row = fc + ((size_t)id * DIN + ih) * DIN + 8 * t;
                    const float4 a4 = *(const float4*)(row);
                    const float4 b4 = *(const float4*)(row + 4);
                    const float  s  = (t > 0) ? row[-1] : 0.0f;   // w = 8t-1 (pad 0)
                    #pragma unroll
                    for (int half = 0; half < 2; ++half) {
                        if ((half == 0 && dd <= 2) || (half == 1 && dd >= 2)) {
                            const int kd = (half == 0) ? dd : dd - 2;
                            const float w0 = w[(kd * 3 + kh) * 3 + 0];
                            const float w1 = w[(kd * 3 + kh) * 3 + 1];
                            const float w2 = w[(kd * 3 + kh) * 3 + 2];
                            acc[half][0] = fmaf(s,    w0, fmaf(a4.x, w1, fmaf(a4.y, w2, acc[half][0])));
                            acc[half][1] = fmaf(a4.y, w0, fmaf(a4.z, w1, fmaf(a4.w, w2, acc[half][1])));
                            acc[half][2] = fmaf(a4.w, w0, fmaf(b4.x, w1, fmaf(b4.y, w2, acc[half][2])));
                            acc[half][3] = fmaf(b4.y, w0, fmaf(b4.z, w1, fmaf(b4.w, w2, acc[half][3])));
                        }
                    }
                }
            }
        }
    }

    const float b = dw_b[c];
    const size_t base = (size_t)c * NPOS + (((size_t)(2 * odp) * DP + oh) * DP) + 4 * t;
    *(float4*)(dwout + base)           = make_float4(acc[0][0] + b, acc[0][1] + b, acc[0][2] + b, acc[0][3] + b);
    *(float4*)(dwout + base + DP * DP) = make_float4(acc[1][0] + b, acc[1][1] + b, acc[1][2] + b, acc[1][3] + b);
}

// ---------------------------------------------------------------------------
// Kernel B (rebuilt): LDS-staged pointwise + V + K.
// Block = 256 threads, 128 positions. Stage dwout[64][128] (32 KB) via
// async global_load_lds width=16 (guaranteed in-flight), then 2 threads/pos
// split the pointwise (16 ch each), exchange through LDS (stride 33,
// conflict-free), split V rows / K heads.
// ---------------------------------------------------------------------------
__global__ __launch_bounds__(256) void pwproj_lds(
    const float* __restrict__ dwout,  // [64][NPOS]
    const float* __restrict__ pw_w,   // [32][64]
    const float* __restrict__ pw_b,   // [32]
    const float* __restrict__ k_w,    // [64][32]
    const float* __restrict__ v_w,    // [64][32]
    float* __restrict__ V,            // [NPOS][64]
    float* __restrict__ Ksc)          // [2][NPOS]
{
    __shared__ float S[NCH * PTILE];  // 32 KB; later reused as f2[128][33]
    const int tid  = threadIdx.x;
    const int pos0 = blockIdx.x * PTILE;

    // ---- async stage: 2048 float4s, 8 per thread ----
    #pragma unroll
    for (int i = 0; i < 8; ++i) {
        const int flat4 = i * 256 + tid;      // 0..2047
        const int row   = flat4 >> 5;         // channel c (32 float4 per row)
        const int col4  = flat4 & 31;
        const float* g  = dwout + (size_t)row * NPOS + pos0 + col4 * 4;
        __builtin_amdgcn_global_load_lds(
            (const __attribute__((address_space(1))) unsigned int*)g,
            (__attribute__((address_space(3))) unsigned int*)&S[flat4 * 4],
            16, 0, 0);
    }
    __syncthreads();

    const int p    = tid & (PTILE - 1);
    const int half = tid >> 7;               // 0 or 1 (wave-uniform)

    // ---- pointwise: my 16 output channels ----
    float f2h[16];
    #pragma unroll
    for (int o = 0; o < 16; ++o) f2h[o] = pw_b[half * 16 + o];
    #pragma unroll
    for (int c = 0; c < NCH; ++c) {
        const float x = S[c * PTILE + p];
        #pragma unroll
        for (int o = 0; o < 16; ++o)
            f2h[o] = fmaf(pw_w[(half * 16 + o) * NCH + c], x, f2h[o]);
    }
    #pragma unroll
    for (int o = 0; o < 16; ++o) f2h[o] = fmaxf(f2h[o], 0.0f);

    __syncthreads();   // everyone done reading staged tile
    #pragma unroll
    for (int o = 0; o < 16; ++o) S[p * 33 + half * 16 + o] = f2h[o];
    __syncthreads();

    // ---- gather full f2 into registers ----
    float f2[NC2];
    #pragma unroll
    for (int o = 0; o < NC2; ++o) f2[o] = S[p * 33 + o];

    // ---- V rows half*32 .. half*32+31 ----
    const int pos = pos0 + p;
    float4* vout = (float4*)(V + (size_t)pos * NCH + half * 32);
    #pragma unroll
    for (int j4 = 0; j4 < 8; ++j4) {
        float4 r;
        float* rp = (float*)&r;
        #pragma unroll
        for (int q = 0; q < 4; ++q) {
            const int j = half * 32 + j4 * 4 + q;
            float a = 0.0f;
            #pragma unroll
            for (int o = 0; o < NC2; ++o) a = fmaf(v_w[j * NC2 + o], f2[o], a);
            rp[q] = a;
        }
        vout[j4] = r;
    }

    // ---- K score for head = half (k_w row half*32) ----
    {
        const float scale = 0.17677669529663687f;
        float a = 0.0f;
        #pragma unroll
        for (int o = 0; o < NC2; ++o) a = fmaf(k_w[(half * 32) * NC2 + o], f2[o], a);
        Ksc[half * NPOS + pos] = a * scale;
    }
}

// ---------------------------------------------------------------------------
// Kernel C: per-center windowed attention + output head (heads in parallel).
// ---------------------------------------------------------------------------
__global__ __launch_bounds__(256) void attn_out(
    const float* __restrict__ V,      // [NPOS][64]
    const float* __restrict__ Ksc,    // [2][NPOS]
    const float* __restrict__ out_w,  // [3][64]
    const float* __restrict__ out_b,  // [3]
    float* __restrict__ out)          // [3][NG]
{
    const int lo_t[12] = {0,1,5,9,14,18,22,26,31,35,39,44};
    const int hi_t[12] = {4,8,12,16,21,25,29,33,38,42,46,48};

    const int g    = blockIdx.x;
    const int tid  = threadIdx.x;
    const int lane = tid & 63;
    const int wv   = tid >> 6;
    const int h    = wv >> 1;         // score-phase head
    const int p    = tid & 127;       // index within head pair, 0..127

    const int gz = g % 12, gy = (g / 12) % 12, gx = g / 144;
    const int lox = lo_t[gx], hix = hi_t[gx];
    const int loy = lo_t[gy], hiy = hi_t[gy];
    const int loz = lo_t[gz], hiz = hi_t[gz];

    __shared__ int   s_flat[WIN3];        // bit31 set => masked out
    __shared__ float s_attn[2][WIN3];
    __shared__ float s_red[4];
    __shared__ float s_red2[4];
    __shared__ float s_gsum[2];
    __shared__ float s_pctx[4][NCH];
    __shared__ float s_ctx[NCH];

    for (int w = tid; w < WIN3; w += 256) {
        int kd = w / 49, kh = (w / 7) % 7, kw = w % 7;
        int ix = lox + kd, iy = loy + kh, iz = loz + kw;
        bool m = (ix < hix) && (iy < hiy) && (iz < hiz);
        if (ix >= hix) ix = lox;
        if (iy >= hiy) iy = loy;
        if (iz >= hiz) iz = loz;
        int flat = (ix * DP + iy) * DP + iz;
        s_flat[w] = m ? flat : (flat | (int)0x80000000);
    }
    __syncthreads();

    const float NEG_INF = -__builtin_inff();

    float sc0 = NEG_INF, sc1 = NEG_INF, sc2 = NEG_INF;
    {
        int fv = s_flat[p];
        if (fv >= 0) sc0 = Ksc[h * NPOS + fv];
        fv = s_flat[p + 128];
        if (fv >= 0) sc1 = Ksc[h * NPOS + fv];
        if (p + 256 < WIN3) {
            fv = s_flat[p + 256];
            if (fv >= 0) sc2 = Ksc[h * NPOS + fv];
        }
    }

    float lmax = fmaxf(fmaxf(sc0, sc1), sc2);
    #pragma unroll
    for (int off = 32; off; off >>= 1) lmax = fmaxf(lmax, __shfl_xor(lmax, off));
    if (lane == 0) s_red[wv] = lmax;
    __syncthreads();
    const float gmax = fmaxf(s_red[2 * h], s_red[2 * h + 1]);

    float e0 = (sc0 == NEG_INF) ? 0.0f : expf(sc0 - gmax);
    float e1 = (sc1 == NEG_INF) ? 0.0f : expf(sc1 - gmax);
    float e2 = 0.0f;
    s_attn[h][p]       = e0;
    s_attn[h][p + 128] = e1;
    if (p + 256 < WIN3) {
        e2 = (sc2 == NEG_INF) ? 0.0f : expf(sc2 - gmax);
        s_attn[h][p + 256] = e2;
    }
    float lsum = e0 + e1 + e2;
    #pragma unroll
    for (int off = 32; off; off >>= 1) lsum += __shfl_xor(lsum, off);
    if (lane == 0) s_red2[wv] = lsum;
    __syncthreads();
    if (tid < 2) s_gsum[tid] = s_red2[2 * tid] + s_red2[2 * tid + 1];
    __syncthreads();

    const int hh = lane >> 5;
    float acc = 0.0f;
    for (int w = wv; w < WIN3; w += 4) {
        int fv = s_flat[w] & 0x7fffffff;
        acc = fmaf(s_attn[hh][w], V[(size_t)fv * NCH + lane], acc);
    }

    s_pctx[wv][lane] = acc;
    __syncthreads();
    if (wv == 0) {
        float ctx = s_pctx[0][lane] + s_pctx[1][lane] + s_pctx[2][lane] + s_pctx[3][lane];
        s_ctx[lane] = ctx / s_gsum[hh];
    }
    __syncthreads();

    if (tid < 3) {
        float a = out_b[tid];
        #pragma unroll
        for (int j = 0; j < NCH; ++j) a = fmaf(out_w[tid * NCH + j], s_ctx[j], a);
        out[tid * NG + g] = a;
    }
}

// ---------------------------------------------------------------------------
extern "C" void kernel_launch(void* const* d_in, const int* in_sizes, int n_in,
                              void* d_out, int out_size, void* d_ws, size_t ws_size,
                              hipStream_t stream) {
    const float* feat  = (const float*)d_in[0];
    const float* dw_w  = (const float*)d_in[1];
    const float* dw_b  = (const float*)d_in[2];
    const float* pw_w  = (const float*)d_in[3];
    const float* pw_b  = (const float*)d_in[4];
    const float* k_w   = (const float*)d_in[5];
    const float* v_w   = (const float*)d_in[6];
    const float* out_w = (const float*)d_in[7];
    const float* out_b = (const float*)d_in[8];
    float* out = (float*)d_out;

    float* dwout = (float*)d_ws;                        // [64][NPOS]
    float* V     = dwout + (size_t)NCH * NPOS;          // [NPOS][64]
    float* Ksc   = V + (size_t)NPOS * NCH;              // [2][NPOS]

    hipLaunchKernelGGL(dwconv8, dim3(54, NCH), dim3(256), 0, stream,
                       feat, dw_w, dw_b, dwout);
    hipLaunchKernelGGL(pwproj_lds, dim3(NPOS / PTILE), dim3(256), 0, stream,
                       dwout, pw_w, pw_b, k_w, v_w, V, Ksc);
    hipLaunchKernelGGL(attn_out, dim3(NG), dim3(256), 0, stream,
                       V, Ksc, out_w, out_b, out);
}

// Round 6
// 138.878 us; speedup vs baseline: 1.1523x; 1.1523x over previous
//
#include <hip/hip_runtime.h>
#include <stdint.h>

#define DIN 96
#define DP 48
#define NPOS (48*48*48)   // 110592
#define NG 1728           // 12^3
#define WIN3 343
#define NCH 64
#define NC2 32

// ---------------------------------------------------------------------------
// Kernel A: depthwise 3x3x3 stride-2 pad-1 conv + bias -> dwout[c][pos]
// 2(d) x 1(h) x 4(w) micro-tile per thread; at HBM roofline (~183 MB fetch).
// ---------------------------------------------------------------------------
__global__ __launch_bounds__(256) void dwconv8(
    const float* __restrict__ feat,   // [64][96][96][96]
    const float* __restrict__ dw_w,   // [64][27]
    const float* __restrict__ dw_b,   // [64]
    float* __restrict__ dwout)        // [64][NPOS]
{
    const int c   = blockIdx.y;
    const int idx = blockIdx.x * 256 + threadIdx.x;   // 0..13823
    const int t   = idx % 12;                         // w-quad (out w = 4t..4t+3)
    const int oh  = (idx / 12) % 48;
    const int odp = idx / (12 * 48);                  // d-pair (out d = 2odp,2odp+1)

    const float* fc = feat + (size_t)c * (DIN * DIN * DIN);
    const float* wc = dw_w + c * 27;
    float w[27];
    #pragma unroll
    for (int i = 0; i < 27; ++i) w[i] = wc[i];        // wave-uniform

    float acc[2][4];
    #pragma unroll
    for (int i = 0; i < 2; ++i)
        #pragma unroll
        for (int j = 0; j < 4; ++j) acc[i][j] = 0.0f;

    #pragma unroll
    for (int dd = 0; dd < 5; ++dd) {
        const int id = 4 * odp - 1 + dd;              // input plane
        if (id >= 0) {
            #pragma unroll
            for (int kh = 0; kh < 3; ++kh) {
                const int ih = 2 * oh - 1 + kh;       // input row
                if (ih >= 0) {
                    const float* row = fc + ((size_t)id * DIN + ih) * DIN + 8 * t;
                    const float4 a4 = *(const float4*)(row);
                    const float4 b4 = *(const float4*)(row + 4);
                    const float  s  = (t > 0) ? row[-1] : 0.0f;   // w = 8t-1 (pad 0)
                    #pragma unroll
                    for (int half = 0; half < 2; ++half) {
                        if ((half == 0 && dd <= 2) || (half == 1 && dd >= 2)) {
                            const int kd = (half == 0) ? dd : dd - 2;
                            const float w0 = w[(kd * 3 + kh) * 3 + 0];
                            const float w1 = w[(kd * 3 + kh) * 3 + 1];
                            const float w2 = w[(kd * 3 + kh) * 3 + 2];
                            acc[half][0] = fmaf(s,    w0, fmaf(a4.x, w1, fmaf(a4.y, w2, acc[half][0])));
                            acc[half][1] = fmaf(a4.y, w0, fmaf(a4.z, w1, fmaf(a4.w, w2, acc[half][1])));
                            acc[half][2] = fmaf(a4.w, w0, fmaf(b4.x, w1, fmaf(b4.y, w2, acc[half][2])));
                            acc[half][3] = fmaf(b4.y, w0, fmaf(b4.z, w1, fmaf(b4.w, w2, acc[half][3])));
                        }
                    }
                }
            }
        }
    }

    const float b = dw_b[c];
    const size_t base = (size_t)c * NPOS + (((size_t)(2 * odp) * DP + oh) * DP) + 4 * t;
    *(float4*)(dwout + base)           = make_float4(acc[0][0] + b, acc[0][1] + b, acc[0][2] + b, acc[0][3] + b);
    *(float4*)(dwout + base + DP * DP) = make_float4(acc[1][0] + b, acc[1][1] + b, acc[1][2] + b, acc[1][3] + b);
}

// ---------------------------------------------------------------------------
// Kernel B1: pointwise (64->32) + bias + ReLU -> f2buf[pos][32]
// 8 threads per position, 4 output channels each. 3456 blocks.
// Weights transposed into LDS (broadcast reads), tiny per-thread state.
// ---------------------------------------------------------------------------
__global__ __launch_bounds__(256) void pw1(
    const float* __restrict__ dwout,  // [64][NPOS]
    const float* __restrict__ pw_w,   // [32][64]
    const float* __restrict__ pw_b,   // [32]
    float* __restrict__ f2buf)        // [NPOS][32]
{
    __shared__ float swT[NCH * NC2];  // swT[c*32+o] = pw_w[o*64+c]
    __shared__ float sb[NC2];
    const int tid = threadIdx.x;

    for (int i = tid; i < NCH * NC2; i += 256) {
        const int o = i & 31, c = i >> 5;
        swT[i] = pw_w[o * NCH + c];
    }
    if (tid < NC2) sb[tid] = pw_b[tid];
    __syncthreads();

    const int g   = blockIdx.x * 256 + tid;
    const int pos = g >> 3;
    const int oq  = g & 7;            // my 4 out-channels: 4*oq .. 4*oq+3

    float a0 = sb[oq * 4 + 0], a1 = sb[oq * 4 + 1];
    float a2 = sb[oq * 4 + 2], a3 = sb[oq * 4 + 3];

    #pragma unroll 8
    for (int c = 0; c < NCH; ++c) {
        const float  x  = dwout[(size_t)c * NPOS + pos];
        const float4 w4 = *(const float4*)&swT[c * NC2 + oq * 4];
        a0 = fmaf(w4.x, x, a0);
        a1 = fmaf(w4.y, x, a1);
        a2 = fmaf(w4.z, x, a2);
        a3 = fmaf(w4.w, x, a3);
    }

    *(float4*)&f2buf[(size_t)pos * NC2 + oq * 4] =
        make_float4(fmaxf(a0, 0.f), fmaxf(a1, 0.f), fmaxf(a2, 0.f), fmaxf(a3, 0.f));
}

// ---------------------------------------------------------------------------
// Kernel B2: V projection (32->64) -> V[pos][64], K score -> Ksc[2][NPOS]
// 4 threads per position, 16 V-rows each. 1728 blocks.
// ---------------------------------------------------------------------------
__global__ __launch_bounds__(256) void pw2(
    const float* __restrict__ f2buf,  // [NPOS][32]
    const float* __restrict__ k_w,    // [64][32]
    const float* __restrict__ v_w,    // [64][32]
    float* __restrict__ V,            // [NPOS][64]
    float* __restrict__ Ksc)          // [2][NPOS]
{
    __shared__ float svT[NC2 * NCH];  // svT[o*64+j] = v_w[j*32+o]
    __shared__ float sk[2 * NC2];     // prescaled k rows {0,32}
    const int tid = threadIdx.x;

    for (int i = tid; i < NC2 * NCH; i += 256) {
        const int j = i & 63, o = i >> 6;
        svT[i] = v_w[j * NC2 + o];
    }
    if (tid < 64) {
        const int h = tid >> 5, o = tid & 31;
        sk[tid] = k_w[(h * 32) * NC2 + o] * 0.17677669529663687f;
    }
    __syncthreads();

    const int g   = blockIdx.x * 256 + tid;
    const int pos = g >> 2;
    const int q3  = g & 3;            // my 16 V-rows: 16*q3 .. 16*q3+15

    float acc[16];
    #pragma unroll
    for (int i = 0; i < 16; ++i) acc[i] = 0.f;
    float kacc = 0.f;
    const int hclamp = q3 & 1;        // safe LDS index; value used only if q3<2

    #pragma unroll
    for (int o4 = 0; o4 < 8; ++o4) {
        const float4 x4 = *(const float4*)&f2buf[(size_t)pos * NC2 + o4 * 4];
        const float xs[4] = {x4.x, x4.y, x4.z, x4.w};
        #pragma unroll
        for (int q = 0; q < 4; ++q) {
            const int o = o4 * 4 + q;
            const float x = xs[q];
            const float* wr = &svT[o * NCH + q3 * 16];
            #pragma unroll
            for (int i = 0; i < 16; ++i) acc[i] = fmaf(wr[i], x, acc[i]);
            const float kw = sk[hclamp * NC2 + o];
            kacc = fmaf((q3 < 2) ? kw : 0.f, x, kacc);
        }
    }

    float4* vout = (float4*)(V + (size_t)pos * NCH + q3 * 16);
    vout[0] = make_float4(acc[0],  acc[1],  acc[2],  acc[3]);
    vout[1] = make_float4(acc[4],  acc[5],  acc[6],  acc[7]);
    vout[2] = make_float4(acc[8],  acc[9],  acc[10], acc[11]);
    vout[3] = make_float4(acc[12], acc[13], acc[14], acc[15]);
    if (q3 < 2) Ksc[(size_t)q3 * NPOS + pos] = kacc;
}

// ---------------------------------------------------------------------------
// Kernel C: per-center windowed attention + output head (heads in parallel).
// ---------------------------------------------------------------------------
__global__ __launch_bounds__(256) void attn_out(
    const float* __restrict__ V,      // [NPOS][64]
    const float* __restrict__ Ksc,    // [2][NPOS]
    const float* __restrict__ out_w,  // [3][64]
    const float* __restrict__ out_b,  // [3]
    float* __restrict__ out)          // [3][NG]
{
    const int lo_t[12] = {0,1,5,9,14,18,22,26,31,35,39,44};
    const int hi_t[12] = {4,8,12,16,21,25,29,33,38,42,46,48};

    const int g    = blockIdx.x;
    const int tid  = threadIdx.x;
    const int lane = tid & 63;
    const int wv   = tid >> 6;
    const int h    = wv >> 1;         // score-phase head
    const int p    = tid & 127;       // index within head pair, 0..127

    const int gz = g % 12, gy = (g / 12) % 12, gx = g / 144;
    const int lox = lo_t[gx], hix = hi_t[gx];
    const int loy = lo_t[gy], hiy = hi_t[gy];
    const int loz = lo_t[gz], hiz = hi_t[gz];

    __shared__ int   s_flat[WIN3];        // bit31 set => masked out
    __shared__ float s_attn[2][WIN3];
    __shared__ float s_red[4];
    __shared__ float s_red2[4];
    __shared__ float s_gsum[2];
    __shared__ float s_pctx[4][NCH];
    __shared__ float s_ctx[NCH];

    for (int w = tid; w < WIN3; w += 256) {
        int kd = w / 49, kh = (w / 7) % 7, kw = w % 7;
        int ix = lox + kd, iy = loy + kh, iz = loz + kw;
        bool m = (ix < hix) && (iy < hiy) && (iz < hiz);
        if (ix >= hix) ix = lox;
        if (iy >= hiy) iy = loy;
        if (iz >= hiz) iz = loz;
        int flat = (ix * DP + iy) * DP + iz;
        s_flat[w] = m ? flat : (flat | (int)0x80000000);
    }
    __syncthreads();

    const float NEG_INF = -__builtin_inff();

    float sc0 = NEG_INF, sc1 = NEG_INF, sc2 = NEG_INF;
    {
        int fv = s_flat[p];
        if (fv >= 0) sc0 = Ksc[h * NPOS + fv];
        fv = s_flat[p + 128];
        if (fv >= 0) sc1 = Ksc[h * NPOS + fv];
        if (p + 256 < WIN3) {
            fv = s_flat[p + 256];
            if (fv >= 0) sc2 = Ksc[h * NPOS + fv];
        }
    }

    float lmax = fmaxf(fmaxf(sc0, sc1), sc2);
    #pragma unroll
    for (int off = 32; off; off >>= 1) lmax = fmaxf(lmax, __shfl_xor(lmax, off));
    if (lane == 0) s_red[wv] = lmax;
    __syncthreads();
    const float gmax = fmaxf(s_red[2 * h], s_red[2 * h + 1]);

    float e0 = (sc0 == NEG_INF) ? 0.0f : expf(sc0 - gmax);
    float e1 = (sc1 == NEG_INF) ? 0.0f : expf(sc1 - gmax);
    float e2 = 0.0f;
    s_attn[h][p]       = e0;
    s_attn[h][p + 128] = e1;
    if (p + 256 < WIN3) {
        e2 = (sc2 == NEG_INF) ? 0.0f : expf(sc2 - gmax);
        s_attn[h][p + 256] = e2;
    }
    float lsum = e0 + e1 + e2;
    #pragma unroll
    for (int off = 32; off; off >>= 1) lsum += __shfl_xor(lsum, off);
    if (lane == 0) s_red2[wv] = lsum;
    __syncthreads();
    if (tid < 2) s_gsum[tid] = s_red2[2 * tid] + s_red2[2 * tid + 1];
    __syncthreads();

    const int hh = lane >> 5;
    float acc = 0.0f;
    for (int w = wv; w < WIN3; w += 4) {
        int fv = s_flat[w] & 0x7fffffff;
        acc = fmaf(s_attn[hh][w], V[(size_t)fv * NCH + lane], acc);
    }

    s_pctx[wv][lane] = acc;
    __syncthreads();
    if (wv == 0) {
        float ctx = s_pctx[0][lane] + s_pctx[1][lane] + s_pctx[2][lane] + s_pctx[3][lane];
        s_ctx[lane] = ctx / s_gsum[hh];
    }
    __syncthreads();

    if (tid < 3) {
        float a = out_b[tid];
        #pragma unroll
        for (int j = 0; j < NCH; ++j) a = fmaf(out_w[tid * NCH + j], s_ctx[j], a);
        out[tid * NG + g] = a;
    }
}

// ---------------------------------------------------------------------------
extern "C" void kernel_launch(void* const* d_in, const int* in_sizes, int n_in,
                              void* d_out, int out_size, void* d_ws, size_t ws_size,
                              hipStream_t stream) {
    const float* feat  = (const float*)d_in[0];
    const float* dw_w  = (const float*)d_in[1];
    const float* dw_b  = (const float*)d_in[2];
    const float* pw_w  = (const float*)d_in[3];
    const float* pw_b  = (const float*)d_in[4];
    const float* k_w   = (const float*)d_in[5];
    const float* v_w   = (const float*)d_in[6];
    const float* out_w = (const float*)d_in[7];
    const float* out_b = (const float*)d_in[8];
    float* out = (float*)d_out;

    float* dwout = (float*)d_ws;                        // [64][NPOS]   28 MB
    float* f2buf = dwout + (size_t)NCH * NPOS;          // [NPOS][32]   14 MB
    float* V     = f2buf + (size_t)NPOS * NC2;          // [NPOS][64]   28 MB
    float* Ksc   = V + (size_t)NPOS * NCH;              // [2][NPOS]    .9 MB

    hipLaunchKernelGGL(dwconv8, dim3(54, NCH), dim3(256), 0, stream,
                       feat, dw_w, dw_b, dwout);
    hipLaunchKernelGGL(pw1, dim3(NPOS * 8 / 256), dim3(256), 0, stream,
                       dwout, pw_w, pw_b, f2buf);
    hipLaunchKernelGGL(pw2, dim3(NPOS * 4 / 256), dim3(256), 0, stream,
                       f2buf, k_w, v_w, V, Ksc);
    hipLaunchKernelGGL(attn_out, dim3(NG), dim3(256), 0, stream,
                       V, Ksc, out_w, out_b, out);
}

// Round 7
// 133.667 us; speedup vs baseline: 1.1973x; 1.0390x over previous
//
#include <hip/hip_runtime.h>
#include <stdint.h>

#define DIN 96
#define DP 48
#define NPOS (48*48*48)   // 110592
#define NG 1728           // 12^3
#define WIN3 343
#define NCH 64
#define NC2 32

// ---------------------------------------------------------------------------
// Kernel A: depthwise 3x3x3 stride-2 pad-1 conv + bias -> dwout[c][pos]
// 2(d) x 1(h) x 4(w) micro-tile per thread; ~HBM-bound (~183 MB fetch).
// ---------------------------------------------------------------------------
__global__ __launch_bounds__(256) void dwconv8(
    const float* __restrict__ feat,   // [64][96][96][96]
    const float* __restrict__ dw_w,   // [64][27]
    const float* __restrict__ dw_b,   // [64]
    float* __restrict__ dwout)        // [64][NPOS]
{
    const int c   = blockIdx.y;
    const int idx = blockIdx.x * 256 + threadIdx.x;   // 0..13823
    const int t   = idx % 12;                         // w-quad (out w = 4t..4t+3)
    const int oh  = (idx / 12) % 48;
    const int odp = idx / (12 * 48);                  // d-pair (out d = 2odp,2odp+1)

    const float* fc = feat + (size_t)c * (DIN * DIN * DIN);
    const float* wc = dw_w + c * 27;
    float w[27];
    #pragma unroll
    for (int i = 0; i < 27; ++i) w[i] = wc[i];        // wave-uniform

    float acc[2][4];
    #pragma unroll
    for (int i = 0; i < 2; ++i)
        #pragma unroll
        for (int j = 0; j < 4; ++j) acc[i][j] = 0.0f;

    #pragma unroll
    for (int dd = 0; dd < 5; ++dd) {
        const int id = 4 * odp - 1 + dd;              // input plane
        if (id >= 0) {
            #pragma unroll
            for (int kh = 0; kh < 3; ++kh) {
                const int ih = 2 * oh - 1 + kh;       // input row
                if (ih >= 0) {
                    const float* row = fc + ((size_t)id * DIN + ih) * DIN + 8 * t;
                    const float4 a4 = *(const float4*)(row);
                    const float4 b4 = *(const float4*)(row + 4);
                    const float  s  = (t > 0) ? row[-1] : 0.0f;   // w = 8t-1 (pad 0)
                    #pragma unroll
                    for (int half = 0; half < 2; ++half) {
                        if ((half == 0 && dd <= 2) || (half == 1 && dd >= 2)) {
                            const int kd = (half == 0) ? dd : dd - 2;
                            const float w0 = w[(kd * 3 + kh) * 3 + 0];
                            const float w1 = w[(kd * 3 + kh) * 3 + 1];
                            const float w2 = w[(kd * 3 + kh) * 3 + 2];
                            acc[half][0] = fmaf(s,    w0, fmaf(a4.x, w1, fmaf(a4.y, w2, acc[half][0])));
                            acc[half][1] = fmaf(a4.y, w0, fmaf(a4.z, w1, fmaf(a4.w, w2, acc[half][1])));
                            acc[half][2] = fmaf(a4.w, w0, fmaf(b4.x, w1, fmaf(b4.y, w2, acc[half][2])));
                            acc[half][3] = fmaf(b4.y, w0, fmaf(b4.z, w1, fmaf(b4.w, w2, acc[half][3])));
                        }
                    }
                }
            }
        }
    }

    const float b = dw_b[c];
    const size_t base = (size_t)c * NPOS + (((size_t)(2 * odp) * DP + oh) * DP) + 4 * t;
    *(float4*)(dwout + base)           = make_float4(acc[0][0] + b, acc[0][1] + b, acc[0][2] + b, acc[0][3] + b);
    *(float4*)(dwout + base + DP * DP) = make_float4(acc[1][0] + b, acc[1][1] + b, acc[1][2] + b, acc[1][3] + b);
}

// ---------------------------------------------------------------------------
// Kernel B1: pointwise (64->32)+bias+ReLU -> f2T[32][NPOS] (transposed!)
// Thread = 4 out-ch x 4 positions (16 accs). Per c-iter:
//   1 float4 x-load + 1 ds_read_b128 weights + 16 FMA.
// ---------------------------------------------------------------------------
__global__ __launch_bounds__(256) void pw1(
    const float* __restrict__ dwout,  // [64][NPOS]
    const float* __restrict__ pw_w,   // [32][64]
    const float* __restrict__ pw_b,   // [32]
    float* __restrict__ f2T)          // [32][NPOS]
{
    __shared__ float swT[NCH * NC2];  // swT[c*32+o] = pw_w[o*64+c]
    __shared__ float sb[NC2];
    const int tid = threadIdx.x;

    for (int i = tid; i < NCH * NC2; i += 256) {
        const int o = i & 31, c = i >> 5;
        swT[i] = pw_w[o * NCH + c];
    }
    if (tid < NC2) sb[tid] = pw_b[tid];
    __syncthreads();

    const int g  = blockIdx.x * 256 + tid;
    const int oq = g & 7;             // out-ch group: 4*oq .. 4*oq+3
    const int p4 = g >> 3;            // positions 4*p4 .. 4*p4+3

    float acc[4][4];                  // [ch][pos]
    #pragma unroll
    for (int i = 0; i < 4; ++i) {
        const float b = sb[oq * 4 + i];
        #pragma unroll
        for (int j = 0; j < 4; ++j) acc[i][j] = b;
    }

    const float* xp = dwout + 4 * (size_t)p4;
    #pragma unroll 4
    for (int c = 0; c < NCH; ++c) {
        const float4 x4 = *(const float4*)(xp + (size_t)c * NPOS);
        const float4 w4 = *(const float4*)(swT + c * NC2 + oq * 4);
        const float xs[4] = {x4.x, x4.y, x4.z, x4.w};
        const float ws[4] = {w4.x, w4.y, w4.z, w4.w};
        #pragma unroll
        for (int i = 0; i < 4; ++i)
            #pragma unroll
            for (int j = 0; j < 4; ++j)
                acc[i][j] = fmaf(ws[i], xs[j], acc[i][j]);
    }

    #pragma unroll
    for (int i = 0; i < 4; ++i) {
        const int o = oq * 4 + i;
        *(float4*)(f2T + (size_t)o * NPOS + 4 * p4) =
            make_float4(fmaxf(acc[i][0], 0.f), fmaxf(acc[i][1], 0.f),
                        fmaxf(acc[i][2], 0.f), fmaxf(acc[i][3], 0.f));
    }
}

// ---------------------------------------------------------------------------
// Kernel B2: V projection (32->64) -> V[pos][64]
// Thread = 8 V-rows x 2 positions (16 accs). Per o-iter:
//   1 float2 x-load + 2 ds_read_b128 weights + 16 FMA.
// ---------------------------------------------------------------------------
__global__ __launch_bounds__(256) void pw2(
    const float* __restrict__ f2T,    // [32][NPOS]
    const float* __restrict__ v_w,    // [64][32]
    float* __restrict__ V)            // [NPOS][64]
{
    __shared__ float svT[NC2 * NCH];  // svT[o*64+j] = v_w[j*32+o]
    const int tid = threadIdx.x;

    for (int i = tid; i < NC2 * NCH; i += 256) {
        const int j = i & 63, o = i >> 6;
        svT[i] = v_w[j * NC2 + o];
    }
    __syncthreads();

    const int g  = blockIdx.x * 256 + tid;
    const int jq = g & 7;             // V-row group: 8*jq .. 8*jq+7
    const int p2 = g >> 3;            // positions 2*p2, 2*p2+1

    float acc[8][2];
    #pragma unroll
    for (int i = 0; i < 8; ++i) { acc[i][0] = 0.f; acc[i][1] = 0.f; }

    const float* xp = f2T + 2 * (size_t)p2;
    #pragma unroll 4
    for (int o = 0; o < NC2; ++o) {
        const float2 x2 = *(const float2*)(xp + (size_t)o * NPOS);
        const float4 wA = *(const float4*)(svT + o * NCH + jq * 8);
        const float4 wB = *(const float4*)(svT + o * NCH + jq * 8 + 4);
        const float ws[8] = {wA.x, wA.y, wA.z, wA.w, wB.x, wB.y, wB.z, wB.w};
        #pragma unroll
        for (int i = 0; i < 8; ++i) {
            acc[i][0] = fmaf(ws[i], x2.x, acc[i][0]);
            acc[i][1] = fmaf(ws[i], x2.y, acc[i][1]);
        }
    }

    #pragma unroll
    for (int pp = 0; pp < 2; ++pp) {
        float* vp = V + (size_t)(2 * p2 + pp) * NCH + jq * 8;
        *(float4*)(vp)     = make_float4(acc[0][pp], acc[1][pp], acc[2][pp], acc[3][pp]);
        *(float4*)(vp + 4) = make_float4(acc[4][pp], acc[5][pp], acc[6][pp], acc[7][pp]);
    }
}

// ---------------------------------------------------------------------------
// Kernel B3: K scores (prescaled rows 0,32 of k_w) -> Ksc[2][NPOS]
// ---------------------------------------------------------------------------
__global__ __launch_bounds__(256) void ksc_k(
    const float* __restrict__ f2T,    // [32][NPOS]
    const float* __restrict__ k_w,    // [64][32]
    float* __restrict__ Ksc)          // [2][NPOS]
{
    __shared__ float sk[NC2 * 2];     // sk[o*2+h]
    const int tid = threadIdx.x;
    if (tid < 64) {
        const int o = tid >> 1, h = tid & 1;
        sk[tid] = k_w[(h * 32) * NC2 + o] * 0.17677669529663687f;
    }
    __syncthreads();

    const int pos = blockIdx.x * 256 + tid;
    float k0 = 0.f, k1 = 0.f;
    #pragma unroll 8
    for (int o = 0; o < NC2; ++o) {
        const float x = f2T[(size_t)o * NPOS + pos];
        k0 = fmaf(sk[o * 2 + 0], x, k0);
        k1 = fmaf(sk[o * 2 + 1], x, k1);
    }
    Ksc[pos] = k0;
    Ksc[NPOS + pos] = k1;
}

// ---------------------------------------------------------------------------
// Kernel C: per-center windowed attention + output head (heads in parallel).
// ---------------------------------------------------------------------------
__global__ __launch_bounds__(256) void attn_out(
    const float* __restrict__ V,      // [NPOS][64]
    const float* __restrict__ Ksc,    // [2][NPOS]
    const float* __restrict__ out_w,  // [3][64]
    const float* __restrict__ out_b,  // [3]
    float* __restrict__ out)          // [3][NG]
{
    const int lo_t[12] = {0,1,5,9,14,18,22,26,31,35,39,44};
    const int hi_t[12] = {4,8,12,16,21,25,29,33,38,42,46,48};

    const int g    = blockIdx.x;
    const int tid  = threadIdx.x;
    const int lane = tid & 63;
    const int wv   = tid >> 6;
    const int h    = wv >> 1;         // score-phase head
    const int p    = tid & 127;       // index within head pair, 0..127

    const int gz = g % 12, gy = (g / 12) % 12, gx = g / 144;
    const int lox = lo_t[gx], hix = hi_t[gx];
    const int loy = lo_t[gy], hiy = hi_t[gy];
    const int loz = lo_t[gz], hiz = hi_t[gz];

    __shared__ int   s_flat[WIN3];        // bit31 set => masked out
    __shared__ float s_attn[2][WIN3];
    __shared__ float s_red[4];
    __shared__ float s_red2[4];
    __shared__ float s_gsum[2];
    __shared__ float s_pctx[4][NCH];
    __shared__ float s_ctx[NCH];

    for (int w = tid; w < WIN3; w += 256) {
        int kd = w / 49, kh = (w / 7) % 7, kw = w % 7;
        int ix = lox + kd, iy = loy + kh, iz = loz + kw;
        bool m = (ix < hix) && (iy < hiy) && (iz < hiz);
        if (ix >= hix) ix = lox;
        if (iy >= hiy) iy = loy;
        if (iz >= hiz) iz = loz;
        int flat = (ix * DP + iy) * DP + iz;
        s_flat[w] = m ? flat : (flat | (int)0x80000000);
    }
    __syncthreads();

    const float NEG_INF = -__builtin_inff();

    float sc0 = NEG_INF, sc1 = NEG_INF, sc2 = NEG_INF;
    {
        int fv = s_flat[p];
        if (fv >= 0) sc0 = Ksc[h * NPOS + fv];
        fv = s_flat[p + 128];
        if (fv >= 0) sc1 = Ksc[h * NPOS + fv];
        if (p + 256 < WIN3) {
            fv = s_flat[p + 256];
            if (fv >= 0) sc2 = Ksc[h * NPOS + fv];
        }
    }

    float lmax = fmaxf(fmaxf(sc0, sc1), sc2);
    #pragma unroll
    for (int off = 32; off; off >>= 1) lmax = fmaxf(lmax, __shfl_xor(lmax, off));
    if (lane == 0) s_red[wv] = lmax;
    __syncthreads();
    const float gmax = fmaxf(s_red[2 * h], s_red[2 * h + 1]);

    float e0 = (sc0 == NEG_INF) ? 0.0f : expf(sc0 - gmax);
    float e1 = (sc1 == NEG_INF) ? 0.0f : expf(sc1 - gmax);
    float e2 = 0.0f;
    s_attn[h][p]       = e0;
    s_attn[h][p + 128] = e1;
    if (p + 256 < WIN3) {
        e2 = (sc2 == NEG_INF) ? 0.0f : expf(sc2 - gmax);
        s_attn[h][p + 256] = e2;
    }
    float lsum = e0 + e1 + e2;
    #pragma unroll
    for (int off = 32; off; off >>= 1) lsum += __shfl_xor(lsum, off);
    if (lane == 0) s_red2[wv] = lsum;
    __syncthreads();
    if (tid < 2) s_gsum[tid] = s_red2[2 * tid] + s_red2[2 * tid + 1];
    __syncthreads();

    const int hh = lane >> 5;
    float acc = 0.0f;
    for (int w = wv; w < WIN3; w += 4) {
        int fv = s_flat[w] & 0x7fffffff;
        acc = fmaf(s_attn[hh][w], V[(size_t)fv * NCH + lane], acc);
    }

    s_pctx[wv][lane] = acc;
    __syncthreads();
    if (wv == 0) {
        float ctx = s_pctx[0][lane] + s_pctx[1][lane] + s_pctx[2][lane] + s_pctx[3][lane];
        s_ctx[lane] = ctx / s_gsum[hh];
    }
    __syncthreads();

    if (tid < 3) {
        float a = out_b[tid];
        #pragma unroll
        for (int j = 0; j < NCH; ++j) a = fmaf(out_w[tid * NCH + j], s_ctx[j], a);
        out[tid * NG + g] = a;
    }
}

// ---------------------------------------------------------------------------
extern "C" void kernel_launch(void* const* d_in, const int* in_sizes, int n_in,
                              void* d_out, int out_size, void* d_ws, size_t ws_size,
                              hipStream_t stream) {
    const float* feat  = (const float*)d_in[0];
    const float* dw_w  = (const float*)d_in[1];
    const float* dw_b  = (const float*)d_in[2];
    const float* pw_w  = (const float*)d_in[3];
    const float* pw_b  = (const float*)d_in[4];
    const float* k_w   = (const float*)d_in[5];
    const float* v_w   = (const float*)d_in[6];
    const float* out_w = (const float*)d_in[7];
    const float* out_b = (const float*)d_in[8];
    float* out = (float*)d_out;

    float* dwout = (float*)d_ws;                        // [64][NPOS]   28 MB
    float* f2T   = dwout + (size_t)NCH * NPOS;          // [32][NPOS]   14 MB
    float* V     = f2T + (size_t)NC2 * NPOS;            // [NPOS][64]   28 MB
    float* Ksc   = V + (size_t)NPOS * NCH;              // [2][NPOS]    .9 MB

    hipLaunchKernelGGL(dwconv8, dim3(54, NCH), dim3(256), 0, stream,
                       feat, dw_w, dw_b, dwout);
    hipLaunchKernelGGL(pw1, dim3(NPOS * 2 / 256), dim3(256), 0, stream,   // 864 blocks
                       dwout, pw_w, pw_b, f2T);
    hipLaunchKernelGGL(pw2, dim3(NPOS * 4 / 256), dim3(256), 0, stream,   // 1728 blocks
                       f2T, v_w, V);
    hipLaunchKernelGGL(ksc_k, dim3(NPOS / 256), dim3(256), 0, stream,     // 432 blocks
                       f2T, k_w, Ksc);
    hipLaunchKernelGGL(attn_out, dim3(NG), dim3(256), 0, stream,
                       V, Ksc, out_w, out_b, out);
}